// Round 6
// baseline (1936.377 us; speedup 1.0000x reference)
//
#include <hip/hip_runtime.h>
#include <stdint.h>

#define B_    16
#define N_    4096
#define CPTS  64
#define S_    1024
#define K_    32

typedef __bf16 bf16x8 __attribute__((ext_vector_type(8)));
typedef float  f32x4  __attribute__((ext_vector_type(4)));
typedef unsigned short ushort8 __attribute__((ext_vector_type(8)));

__device__ __forceinline__ float fmul_(float a, float b){ return __fmul_rn(a,b); }
__device__ __forceinline__ float fadd_(float a, float b){ return __fadd_rn(a,b); }
__device__ __forceinline__ float fsub_(float a, float b){ return __fsub_rn(a,b); }

__device__ __forceinline__ unsigned short f2bf(float f){
  unsigned u = __float_as_uint(f);
  unsigned r = (u + 0x7FFFu + ((u >> 16) & 1u)) >> 16;
  return (unsigned short)r;
}

__device__ __forceinline__ f32x4 mfma_16x16x32(bf16x8 a, bf16x8 b, f32x4 c){
  return __builtin_amdgcn_mfma_f32_16x16x32_bf16(a, b, c, 0, 0, 0);
}

__device__ __forceinline__ unsigned long long umin64(unsigned long long a, unsigned long long b){
  return b < a ? b : a;
}
__device__ __forceinline__ unsigned long long umax64(unsigned long long a, unsigned long long b){
  return a < b ? b : a;
}

// DPP lane move: invalid source lanes keep old value (= identity for min/max).
template<int CTRL>
__device__ __forceinline__ unsigned dppmove(unsigned v){
  return (unsigned)__builtin_amdgcn_update_dpp((int)v, (int)v, CTRL, 0xF, 0xF, false);
}
// Wave64 max reduce in the VALU pipe; result broadcast via readlane(63).
__device__ __forceinline__ unsigned wave_umax_dpp(unsigned v){
  unsigned t;
  t = dppmove<0x111>(v); v = v > t ? v : t;   // row_shr:1
  t = dppmove<0x112>(v); v = v > t ? v : t;   // row_shr:2
  t = dppmove<0x114>(v); v = v > t ? v : t;   // row_shr:4
  t = dppmove<0x118>(v); v = v > t ? v : t;   // row_shr:8
  t = dppmove<0x142>(v); v = v > t ? v : t;   // row_bcast:15
  t = dppmove<0x143>(v); v = v > t ? v : t;   // row_bcast:31
  return (unsigned)__builtin_amdgcn_readlane((int)v, 63);
}

// ---------------------------------------------------------------------------
// FPS: TWO batches per block (8 blocks), 256 threads, 16 pts/thread/batch in
// registers. The two batches' scans + DPP reduces interleave so one batch's
// serial latency (barrier, wc read, lp[far] read) hides under the other's
// VALU issue; ONE barrier per step serves both (parity wc buffers).
// fhist[0]=0, fhist[s+1]=winner of step s.
// ---------------------------------------------------------------------------
__global__ __launch_bounds__(256, 1) void fps_kernel(const float* __restrict__ xyz,
                                                     float* __restrict__ out_newxyz)
{
  const int bp  = blockIdx.x;               // batch pair 0..7
  const int tid = threadIdx.x;
  const int wave = tid >> 6;
  __shared__ float4 lpA[N_], lpB[N_];       // 2 x 64 KB
  __shared__ unsigned long long wcA[2][4], wcB[2][4];
  __shared__ int fhA[S_ + 1], fhB[S_ + 1];

  const float* xa = xyz + (size_t)(bp*2+0) * (N_*3);
  const float* xb = xyz + (size_t)(bp*2+1) * (N_*3);
  float pxA[16], pyA[16], pzA[16], dmA[16];
  float pxB[16], pyB[16], pzB[16], dmB[16];
#pragma unroll
  for (int i = 0; i < 16; ++i) {
    int n = i*256 + tid;
    float x = xa[n*3+0], y = xa[n*3+1], z = xa[n*3+2];
    lpA[n] = make_float4(x,y,z,0.0f);
    pxA[i]=x; pyA[i]=y; pzA[i]=z; dmA[i] = INFINITY;
    float x2 = xb[n*3+0], y2 = xb[n*3+1], z2 = xb[n*3+2];
    lpB[n] = make_float4(x2,y2,z2,0.0f);
    pxB[i]=x2; pyB[i]=y2; pzB[i]=z2; dmB[i] = INFINITY;
  }
  if (tid == 0) { fhA[0] = 0; fhB[0] = 0; }
  __syncthreads();

  int farA = 0, farB = 0;
  for (int step = 0; step < S_; ++step) {
    float4 cA = lpA[farA];                  // both reads issue together
    float4 cB = lpB[farB];

    float bvA = -1.0f; unsigned biA = 0;
    float bvB = -1.0f; unsigned biB = 0;
#pragma unroll
    for (int i = 0; i < 16; ++i) {
      float dx = fsub_(pxA[i],cA.x), dy = fsub_(pyA[i],cA.y), dz = fsub_(pzA[i],cA.z);
      float d  = fadd_(fadd_(fmul_(dx,dx),fmul_(dy,dy)),fmul_(dz,dz));
      float dm = fminf(dmA[i], d);
      dmA[i] = dm;
      bool gt = dm > bvA;                   // strict >: lowest i wins ties
      bvA = gt ? dm : bvA;
      biA = gt ? (unsigned)(i*256 + tid) : biA;

      float ex = fsub_(pxB[i],cB.x), ey = fsub_(pyB[i],cB.y), ez = fsub_(pzB[i],cB.z);
      float e  = fadd_(fadd_(fmul_(ex,ex),fmul_(ey,ey)),fmul_(ez,ez));
      float em = fminf(dmB[i], e);
      dmB[i] = em;
      bool gt2 = em > bvB;
      bvB = gt2 ? em : bvB;
      biB = gt2 ? (unsigned)(i*256 + tid) : biB;
    }
    // Phase A: wave max of distance bits (nonneg -> order-monotone bits)
    unsigned bvbA = __float_as_uint(bvA);
    unsigned bvbB = __float_as_uint(bvB);
    unsigned wmA = wave_umax_dpp(bvbA);
    unsigned wmB = wave_umax_dpp(bvbB);
    // Phase B: min index among maxima (max of ~idx; 0 = identity)
    unsigned wiA = wave_umax_dpp((bvbA == wmA) ? ~biA : 0u);
    unsigned wiB = wave_umax_dpp((bvbB == wmB) ? ~biB : 0u);
    unsigned long long kvA = ((unsigned long long)wmA << 32) | wiA;
    unsigned long long kvB = ((unsigned long long)wmB << 32) | wiB;

    int par = step & 1;
    if ((tid & 63) == 0) { wcA[par][wave] = kvA; wcB[par][wave] = kvB; }
    __syncthreads();
    unsigned long long a0 = umax64(wcA[par][0], wcA[par][1]);
    unsigned long long a1 = umax64(wcA[par][2], wcA[par][3]);
    unsigned long long b0 = umax64(wcB[par][0], wcB[par][1]);
    unsigned long long b1 = umax64(wcB[par][2], wcB[par][3]);
    farA = (int)(~(unsigned)umax64(a0, a1));
    farB = (int)(~(unsigned)umax64(b0, b1));
    if (tid == 0) { fhA[step + 1] = farA; fhB[step + 1] = farB; }
  }
  __syncthreads();

  // epilogue: write both batches' centroids coalesced
  float* oa = out_newxyz + (size_t)(bp*2+0)*S_*3;
  float* ob = out_newxyz + (size_t)(bp*2+1)*S_*3;
#pragma unroll
  for (int j = 0; j < 4; ++j) {
    int s = j*256 + tid;
    float4 p = lpA[fhA[s]];
    oa[s*3+0] = p.x; oa[s*3+1] = p.y; oa[s*3+2] = p.z;
    float4 q = lpB[fhB[s]];
    ob[s*3+0] = q.x; ob[s*3+1] = q.y; ob[s*3+2] = q.z;
  }
}

// ---------------------------------------------------------------------------
// kNN: top-32 of 4096 per query, wave-per-query, exact with top_k tie-break.
// ---------------------------------------------------------------------------
#define KNN_REB(G) { \
  if (isw) { \
    if      (jj==0u) sk[(G)*8+0]=0xFFFFFFFFu; else if (jj==1u) sk[(G)*8+1]=0xFFFFFFFFu; \
    else if (jj==2u) sk[(G)*8+2]=0xFFFFFFFFu; else if (jj==3u) sk[(G)*8+3]=0xFFFFFFFFu; \
    else if (jj==4u) sk[(G)*8+4]=0xFFFFFFFFu; else if (jj==5u) sk[(G)*8+5]=0xFFFFFFFFu; \
    else if (jj==6u) sk[(G)*8+6]=0xFFFFFFFFu; else              sk[(G)*8+7]=0xFFFFFFFFu; } \
  { unsigned bk = sk[(G)*8+0]; unsigned bi = (unsigned)(((G)*8+0)*64 + lane); \
    _Pragma("unroll") \
    for (int j2 = 1; j2 < 8; ++j2) { \
      unsigned k2 = sk[(G)*8+j2]; unsigned i2 = (unsigned)(((G)*8+j2)*64 + lane); \
      bool lt = k2 < bk; bk = lt ? k2 : bk; bi = lt ? i2 : bi; } \
    gk[(G)] = bk; gi[(G)] = bi; } }

__global__ __launch_bounds__(256) void knn_kernel(const float* __restrict__ xyz,
                                                  const float* __restrict__ newxyz,
                                                  int* __restrict__ knn)
{
  __shared__ float4 lp[N_];  // x,y,z,dst2  (64 KB exactly)
  const int b     = blockIdx.x >> 6;
  const int chunk = blockIdx.x & 63;
  const float* xb = xyz + (size_t)b * (N_*3);
  for (int e = threadIdx.x; e < N_; e += 256) {
    float x = xb[e*3+0], y = xb[e*3+1], z = xb[e*3+2];
    float d2 = fadd_(fadd_(fmul_(x,x),fmul_(y,y)),fmul_(z,z));
    lp[e] = make_float4(x,y,z,d2);
  }
  __syncthreads();

  const int wave = threadIdx.x >> 6, lane = threadIdx.x & 63;
  for (int qi = 0; qi < 4; ++qi) {
    const int s  = chunk*16 + wave*4 + qi;
    const int fq = b*S_ + s;
    float qx = newxyz[fq*3+0], qy = newxyz[fq*3+1], qz = newxyz[fq*3+2];
    float s2 = fadd_(fadd_(fmul_(qx,qx),fmul_(qy,qy)),fmul_(qz,qz));

    unsigned sk[64];
#pragma unroll
    for (int j = 0; j < 64; ++j) {
      float4 p = lp[j*64 + lane];
      float dot = fadd_(fadd_(fmul_(qx,p.x),fmul_(qy,p.y)),fmul_(qz,p.z));
      float d   = fadd_(fsub_(s2, fmul_(2.0f,dot)), p.w);
      unsigned u = __float_as_uint(d);
      sk[j] = u ^ ((unsigned)((int)u >> 31) | 0x80000000u);  // sortable
    }
    unsigned gk[8], gi[8];
#pragma unroll
    for (int g = 0; g < 8; ++g) {
      unsigned bk = sk[g*8+0], bi = (unsigned)((g*8+0)*64 + lane);
#pragma unroll
      for (int j = 1; j < 8; ++j) {
        unsigned k2 = sk[g*8+j]; unsigned i2 = (unsigned)((g*8+j)*64 + lane);
        bool lt = k2 < bk; bk = lt ? k2 : bk; bi = lt ? i2 : bi;
      }
      gk[g]=bk; gi[g]=bi;
    }
    int* ko = knn + (size_t)fq * K_;
    for (int it = 0; it < K_; ++it) {
      unsigned long long c0 = ((unsigned long long)gk[0] << 32) | gi[0];
      unsigned long long c1 = ((unsigned long long)gk[1] << 32) | gi[1];
      unsigned long long c2 = ((unsigned long long)gk[2] << 32) | gi[2];
      unsigned long long c3 = ((unsigned long long)gk[3] << 32) | gi[3];
      unsigned long long c4 = ((unsigned long long)gk[4] << 32) | gi[4];
      unsigned long long c5 = ((unsigned long long)gk[5] << 32) | gi[5];
      unsigned long long c6 = ((unsigned long long)gk[6] << 32) | gi[6];
      unsigned long long c7 = ((unsigned long long)gk[7] << 32) | gi[7];
      c0 = umin64(c0,c1); c2 = umin64(c2,c3); c4 = umin64(c4,c5); c6 = umin64(c6,c7);
      c0 = umin64(c0,c2); c4 = umin64(c4,c6);
      unsigned long long cand = umin64(c0,c4);
#pragma unroll
      for (int m = 1; m <= 32; m <<= 1) {
        unsigned long long o = __shfl_xor(cand, m, 64);
        cand = (o < cand) ? o : cand;
      }
      unsigned widx = (unsigned)cand;
      if (lane == 0) ko[it] = (int)widx;
      unsigned wl = widx & 63u, wj = widx >> 6;
      unsigned g = wj >> 3, jj = wj & 7u;
      bool isw = (lane == (int)wl);
      switch (g) {
        case 0: KNN_REB(0); break;
        case 1: KNN_REB(1); break;
        case 2: KNN_REB(2); break;
        case 3: KNN_REB(3); break;
        case 4: KNN_REB(4); break;
        case 5: KNN_REB(5); break;
        case 6: KNN_REB(6); break;
        default: KNN_REB(7); break;
      }
    }
  }
}

// ---------------------------------------------------------------------------
// MLP chain: block = 4 queries = 128 rows. bf16 MFMA 16x16x32.
// A layout (K): cols 0..63 = points, 64..66 = xyz-norm, 67..95 = zero.
// W0 rows permuted identically, so the matmul is unchanged.
// ---------------------------------------------------------------------------
template<int KS, int NT>
__device__ __forceinline__ void layer_mfma(const unsigned short* A, const unsigned short* W,
                                           int wstride, f32x4 (&acc)[2][NT], int wave, int lane)
{
  const int quad = lane >> 4, row0 = lane & 15;
  bf16x8 a[2][KS];
#pragma unroll
  for (int m2 = 0; m2 < 2; ++m2)
#pragma unroll
    for (int ks = 0; ks < KS; ++ks)
      a[m2][ks] = *(const bf16x8*)&A[((wave*2+m2)*16 + row0)*104 + ks*32 + quad*8];
#pragma unroll
  for (int m2 = 0; m2 < 2; ++m2)
#pragma unroll
    for (int n = 0; n < NT; ++n)
      acc[m2][n] = (f32x4){0.f,0.f,0.f,0.f};
#pragma unroll
  for (int n = 0; n < NT; ++n) {
#pragma unroll
    for (int ks = 0; ks < KS; ++ks) {
      bf16x8 bfrag = *(const bf16x8*)&W[(n*16 + row0)*wstride + ks*32 + quad*8];
      acc[0][n] = mfma_16x16x32(a[0][ks], bfrag, acc[0][n]);
      acc[1][n] = mfma_16x16x32(a[1][ks], bfrag, acc[1][n]);
    }
  }
}

template<int NT>
__device__ __forceinline__ void stats_ep(const f32x4 (&acc)[2][NT], float* sum, float* sq, int lane)
{
  const int part = blockIdx.x & 63;
  const int col0 = lane & 15;
#pragma unroll
  for (int n = 0; n < NT; ++n) {
    float s = 0.f, q = 0.f;
#pragma unroll
    for (int m2 = 0; m2 < 2; ++m2)
#pragma unroll
      for (int t = 0; t < 4; ++t) { float z = acc[m2][n][t]; s += z; q += z*z; }
    s += __shfl_xor(s, 16, 64); q += __shfl_xor(q, 16, 64);
    s += __shfl_xor(s, 32, 64); q += __shfl_xor(q, 32, 64);
    if (lane < 16) {
      atomicAdd(&sum[part*128 + n*16 + col0], s);
      atomicAdd(&sq [part*128 + n*16 + col0], q);
    }
  }
}

template<int NT>
__device__ __forceinline__ void bn_store(const f32x4 (&acc)[2][NT], unsigned short* A,
                                         const float* lmu, const float* lrsg, const float* lbeta,
                                         int off, int wave, int quad, int col0)
{
#pragma unroll
  for (int n = 0; n < NT; ++n) {
    int c = n*16 + col0;
    float mu = lmu[off+c], rg = lrsg[off+c], bt = lbeta[off+c];
#pragma unroll
    for (int m2 = 0; m2 < 2; ++m2)
#pragma unroll
      for (int t = 0; t < 4; ++t) {
        int row = (wave*2+m2)*16 + quad*4 + t;
        float v = fmaxf((acc[m2][n][t] - mu)*rg + bt, 0.0f);
        A[row*104 + c] = f2bf(v);
      }
  }
}

template<int STAGE>
__global__ __launch_bounds__(256) void mlp_kernel(
    const float* __restrict__ xyz, const float* __restrict__ pts,
    const float* __restrict__ W0, const float* __restrict__ g0, const float* __restrict__ be0,
    const float* __restrict__ W1, const float* __restrict__ g1, const float* __restrict__ be1,
    const float* __restrict__ W2, const float* __restrict__ g2, const float* __restrict__ be2,
    const float* __restrict__ newxyz, const int* __restrict__ knn,
    float* __restrict__ stats, float* __restrict__ out1)
{
  __shared__ unsigned short sA[128*104];   // activations, stride 104 (13x16B -> conflict-free b128)
  __shared__ unsigned short wb[128*72];    // weights (W0 path uses stride 104: 64*104 <= 128*72)
  __shared__ float lmu[256], lrsg[256], lbeta[256];

  const int tid  = threadIdx.x;
  const int wave = tid >> 6, lane = tid & 63;
  const int quad = lane >> 4, col0 = lane & 15;

  // ---- load BN stats of prior layers (tiny) ----
  {
    const int nl = STAGE - 1;
    const int   couts[3] = {64,64,128};
    const int   offs[3]  = {0,64,128};
    const float* gs[3]   = {g0,g1,g2};
    const float* bs[3]   = {be0,be1,be2};
    for (int l = 0; l < nl; ++l) {
      if (tid < couts[l]) {
        const float* su = stats + (size_t)(2*l)*8192;
        const float* sq = stats + (size_t)(2*l+1)*8192;
        float sm = 0.f, q = 0.f;
        for (int p = 0; p < 64; ++p) { sm += su[p*128+tid]; q += sq[p*128+tid]; }
        float mu  = sm * (1.0f/524288.0f);
        float var = q  * (1.0f/524288.0f) - mu*mu;
        float rs  = rsqrtf(var + 1e-5f);
        lmu [offs[l]+tid] = mu;
        lrsg[offs[l]+tid] = rs * gs[l][tid];
        lbeta[offs[l]+tid] = bs[l][tid];
      }
    }
  }

  // ---- gather grouped input into sA (bf16), vectorized ushort8 stores ----
  {
    const int r = tid >> 1, half = tid & 1;
    const int ql = r >> 5, kk = r & 31;
    const int fq = blockIdx.x*4 + ql;
    const int b  = fq >> 10;
    const int p  = knn[(size_t)fq*K_ + kk];
    const float4* p4 = (const float4*)(pts + ((size_t)(b<<12) + p) * CPTS);
    ushort8* arow = (ushort8*)&sA[r*104];   // 208B rows -> 16B aligned
    if (half == 0) {
#pragma unroll
      for (int ch = 0; ch < 4; ++ch) {
        float4 a = p4[ch*2], bq = p4[ch*2+1];
        ushort8 v = { f2bf(a.x),f2bf(a.y),f2bf(a.z),f2bf(a.w),
                      f2bf(bq.x),f2bf(bq.y),f2bf(bq.z),f2bf(bq.w) };
        arow[ch] = v;
      }
    } else {
#pragma unroll
      for (int ch = 4; ch < 8; ++ch) {
        float4 a = p4[ch*2], bq = p4[ch*2+1];
        ushort8 v = { f2bf(a.x),f2bf(a.y),f2bf(a.z),f2bf(a.w),
                      f2bf(bq.x),f2bf(bq.y),f2bf(bq.z),f2bf(bq.w) };
        arow[ch] = v;
      }
      const float* xr = xyz + ((size_t)(b<<12) + p)*3;
      float qx = newxyz[fq*3+0], qy = newxyz[fq*3+1], qz = newxyz[fq*3+2];
      ushort8 vx = { f2bf(fsub_(xr[0],qx)), f2bf(fsub_(xr[1],qy)), f2bf(fsub_(xr[2],qz)),
                     0,0,0,0,0 };
      arow[8] = vx;
      ushort8 z = {0,0,0,0,0,0,0,0};
      arow[9] = z; arow[10] = z; arow[11] = z;
    }
  }

  // ---- W0 -> wb (stride 104, permuted cols, zero-padded) ----
  {
    const int n = tid >> 2, q = tid & 3;
    const float* wr = W0 + n*67;
#pragma unroll
    for (int ch = 0; ch < 3; ++ch) {
      int c0 = q*24 + ch*8;
      ushort8 v;
#pragma unroll
      for (int j = 0; j < 8; ++j) {
        int cc = c0 + j;
        float f = (cc < 64) ? wr[3+cc] : ((cc < 67) ? wr[cc-64] : 0.0f);
        v[j] = f2bf(f);
      }
      *(ushort8*)&wb[n*104 + c0] = v;
    }
  }
  __syncthreads();

  // ---- layer 0: (128 x 96) @ (96 x 64) ----
  f32x4 acc0[2][4];
  layer_mfma<3,4>(sA, wb, 104, acc0, wave, lane);
  __syncthreads();
  if constexpr (STAGE == 1) { stats_ep<4>(acc0, stats + 0*8192, stats + 1*8192, lane); return; }

  bn_store<4>(acc0, sA, lmu, lrsg, lbeta, 0, wave, quad, col0);
  {
    const int n = tid >> 2, k0 = (tid & 3) * 16;
    const float4* w4 = (const float4*)(W1 + n*64 + k0);
#pragma unroll
    for (int i = 0; i < 2; ++i) {
      float4 a = w4[i*2], bq = w4[i*2+1];
      ushort8 v = { f2bf(a.x),f2bf(a.y),f2bf(a.z),f2bf(a.w),
                    f2bf(bq.x),f2bf(bq.y),f2bf(bq.z),f2bf(bq.w) };
      ((ushort8*)&wb[n*72 + k0])[i] = v;
    }
  }
  __syncthreads();

  // ---- layer 1: (128 x 64) @ (64 x 64) ----
  f32x4 acc1[2][4];
  layer_mfma<2,4>(sA, wb, 72, acc1, wave, lane);
  __syncthreads();
  if constexpr (STAGE == 2) { stats_ep<4>(acc1, stats + 2*8192, stats + 3*8192, lane); return; }

  bn_store<4>(acc1, sA, lmu, lrsg, lbeta, 64, wave, quad, col0);
  {
    const int n = tid >> 1, k0 = (tid & 1) * 32;
    const float4* w4 = (const float4*)(W2 + n*64 + k0);
#pragma unroll
    for (int i = 0; i < 4; ++i) {
      float4 a = w4[i*2], bq = w4[i*2+1];
      ushort8 v = { f2bf(a.x),f2bf(a.y),f2bf(a.z),f2bf(a.w),
                    f2bf(bq.x),f2bf(bq.y),f2bf(bq.z),f2bf(bq.w) };
      ((ushort8*)&wb[n*72 + k0])[i] = v;
    }
  }
  __syncthreads();

  // ---- layer 2: (128 x 64) @ (64 x 128) ----
  f32x4 acc2[2][8];
  layer_mfma<2,8>(sA, wb, 72, acc2, wave, lane);
  if constexpr (STAGE == 3) { stats_ep<8>(acc2, stats + 4*8192, stats + 5*8192, lane); return; }

  // ---- final: BN3 + ReLU + max over K (wave == query) ----
  {
    const int fq = blockIdx.x*4 + wave;
#pragma unroll
    for (int n = 0; n < 8; ++n) {
      int c = n*16 + col0;
      float mu = lmu[128+c], rg = lrsg[128+c], bt = lbeta[128+c];
      float mx = -INFINITY;
#pragma unroll
      for (int m2 = 0; m2 < 2; ++m2)
#pragma unroll
        for (int t = 0; t < 4; ++t) {
          float v = fmaxf((acc2[m2][n][t] - mu)*rg + bt, 0.0f);
          mx = fmaxf(mx, v);
        }
      mx = fmaxf(mx, __shfl_xor(mx, 16, 64));
      mx = fmaxf(mx, __shfl_xor(mx, 32, 64));
      if (lane < 16) out1[(size_t)fq*128 + c] = mx;
    }
  }
}

// ---------------------------------------------------------------------------
extern "C" void kernel_launch(void* const* d_in, const int* in_sizes, int n_in,
                              void* d_out, int out_size, void* d_ws, size_t ws_size,
                              hipStream_t stream)
{
  (void)in_sizes; (void)n_in; (void)out_size; (void)ws_size;
  const float* xyz  = (const float*)d_in[0];
  const float* pts  = (const float*)d_in[1];
  const float* W0   = (const float*)d_in[2];
  const float* g0   = (const float*)d_in[3];
  const float* be0  = (const float*)d_in[4];
  const float* W1   = (const float*)d_in[5];
  const float* g1   = (const float*)d_in[6];
  const float* be1  = (const float*)d_in[7];
  const float* W2   = (const float*)d_in[8];
  const float* g2   = (const float*)d_in[9];
  const float* be2  = (const float*)d_in[10];

  float* out  = (float*)d_out;                   // new_xyz: 16*1024*3
  float* out1 = out + (size_t)B_*S_*3;           // features: 16*1024*128
  int*   knn   = (int*)d_ws;                                     // 2 MB
  float* stats = (float*)((char*)d_ws + (size_t)B_*S_*K_*4);     // 6*8192 floats

  hipMemsetAsync(stats, 0, (size_t)6*8192*sizeof(float), stream);
  fps_kernel<<<8, 256, 0, stream>>>(xyz, out);
  knn_kernel<<<1024, 256, 0, stream>>>(xyz, out, knn);
  mlp_kernel<1><<<4096, 256, 0, stream>>>(xyz, pts, W0,g0,be0, W1,g1,be1, W2,g2,be2, out, knn, stats, out1);
  mlp_kernel<2><<<4096, 256, 0, stream>>>(xyz, pts, W0,g0,be0, W1,g1,be1, W2,g2,be2, out, knn, stats, out1);
  mlp_kernel<3><<<4096, 256, 0, stream>>>(xyz, pts, W0,g0,be0, W1,g1,be1, W2,g2,be2, out, knn, stats, out1);
  mlp_kernel<4><<<4096, 256, 0, stream>>>(xyz, pts, W0,g0,be0, W1,g1,be1, W2,g2,be2, out, knn, stats, out1);
}

// Round 7
// 1390.620 us; speedup vs baseline: 1.3925x; 1.3925x over previous
//
#include <hip/hip_runtime.h>
#include <stdint.h>

#define B_    16
#define N_    4096
#define CPTS  64
#define S_    1024
#define K_    32

typedef __bf16 bf16x8 __attribute__((ext_vector_type(8)));
typedef float  f32x4  __attribute__((ext_vector_type(4)));
typedef unsigned short ushort8 __attribute__((ext_vector_type(8)));

__device__ __forceinline__ float fmul_(float a, float b){ return __fmul_rn(a,b); }
__device__ __forceinline__ float fadd_(float a, float b){ return __fadd_rn(a,b); }
__device__ __forceinline__ float fsub_(float a, float b){ return __fsub_rn(a,b); }

__device__ __forceinline__ unsigned short f2bf(float f){
  unsigned u = __float_as_uint(f);
  unsigned r = (u + 0x7FFFu + ((u >> 16) & 1u)) >> 16;
  return (unsigned short)r;
}
__device__ __forceinline__ float bf2f(unsigned short u){
  return __uint_as_float((unsigned)u << 16);
}

__device__ __forceinline__ f32x4 mfma_16x16x32(bf16x8 a, bf16x8 b, f32x4 c){
  return __builtin_amdgcn_mfma_f32_16x16x32_bf16(a, b, c, 0, 0, 0);
}

__device__ __forceinline__ unsigned long long umin64(unsigned long long a, unsigned long long b){
  return b < a ? b : a;
}
__device__ __forceinline__ unsigned long long umax64(unsigned long long a, unsigned long long b){
  return a < b ? b : a;
}

// DPP lane move: invalid source lanes keep old value (= identity for min/max).
template<int CTRL>
__device__ __forceinline__ unsigned dppmove(unsigned v){
  return (unsigned)__builtin_amdgcn_update_dpp((int)v, (int)v, CTRL, 0xF, 0xF, false);
}
__device__ __forceinline__ unsigned wave_umax_dpp(unsigned v){
  unsigned t;
  t = dppmove<0x111>(v); v = v > t ? v : t;
  t = dppmove<0x112>(v); v = v > t ? v : t;
  t = dppmove<0x114>(v); v = v > t ? v : t;
  t = dppmove<0x118>(v); v = v > t ? v : t;
  t = dppmove<0x142>(v); v = v > t ? v : t;
  t = dppmove<0x143>(v); v = v > t ? v : t;
  return (unsigned)__builtin_amdgcn_readlane((int)v, 63);
}

// ---------------------------------------------------------------------------
// FPS (round-5 proven version): one block per batch, 256 threads, 16 pts/thr.
// ---------------------------------------------------------------------------
__global__ __launch_bounds__(256) void fps_kernel(const float* __restrict__ xyz,
                                                  float* __restrict__ out_newxyz)
{
  const int b   = blockIdx.x;
  const int tid = threadIdx.x;
  const int wave = tid >> 6;
  __shared__ float4 lp[N_];
  __shared__ unsigned long long wc[2][4];
  __shared__ int fhist[S_ + 1];

  const float* xb = xyz + (size_t)b * (N_*3);
  float px[16], py[16], pz[16], dmin[16];
#pragma unroll
  for (int i = 0; i < 16; ++i) {
    int n = i*256 + tid;
    float x = xb[n*3+0], y = xb[n*3+1], z = xb[n*3+2];
    lp[n] = make_float4(x,y,z,0.0f);
    px[i]=x; py[i]=y; pz[i]=z;
    dmin[i] = INFINITY;
  }
  if (tid == 0) fhist[0] = 0;
  __syncthreads();

  int far = 0;
  for (int step = 0; step < S_; ++step) {
    float4 cp = lp[far];
    float cx = cp.x, cy = cp.y, cz = cp.z;
    float bv = -1.0f; unsigned bidx = 0;
#pragma unroll
    for (int i = 0; i < 16; ++i) {
      float dx = fsub_(px[i],cx), dy = fsub_(py[i],cy), dz = fsub_(pz[i],cz);
      float d  = fadd_(fadd_(fmul_(dx,dx),fmul_(dy,dy)),fmul_(dz,dz));
      float dm = fminf(dmin[i], d);
      dmin[i] = dm;
      bool gt = dm > bv;
      bv   = gt ? dm : bv;
      bidx = gt ? (unsigned)(i*256 + tid) : bidx;
    }
    unsigned bvb  = __float_as_uint(bv);
    unsigned wmax = wave_umax_dpp(bvb);
    unsigned cand = (bvb == wmax) ? ~bidx : 0u;
    unsigned winv = wave_umax_dpp(cand);
    unsigned long long kv = ((unsigned long long)wmax << 32) | winv;

    int par = step & 1;
    if ((tid & 63) == 0) wc[par][wave] = kv;
    __syncthreads();
    unsigned long long b0 = umax64(wc[par][0], wc[par][1]);
    unsigned long long b1 = umax64(wc[par][2], wc[par][3]);
    far = (int)(~(unsigned)umax64(b0, b1));
    if (tid == 0) fhist[step + 1] = far;
  }
  __syncthreads();

  float* ob = out_newxyz + (size_t)b*S_*3;
#pragma unroll
  for (int j = 0; j < 4; ++j) {
    int s = j*256 + tid;
    float4 p = lp[fhist[s]];
    ob[s*3+0] = p.x; ob[s*3+1] = p.y; ob[s*3+2] = p.z;
  }
}

// ---------------------------------------------------------------------------
// kNN: top-32 of 4096 per query, wave-per-query, exact with top_k tie-break.
// ---------------------------------------------------------------------------
#define KNN_REB(G) { \
  if (isw) { \
    if      (jj==0u) sk[(G)*8+0]=0xFFFFFFFFu; else if (jj==1u) sk[(G)*8+1]=0xFFFFFFFFu; \
    else if (jj==2u) sk[(G)*8+2]=0xFFFFFFFFu; else if (jj==3u) sk[(G)*8+3]=0xFFFFFFFFu; \
    else if (jj==4u) sk[(G)*8+4]=0xFFFFFFFFu; else if (jj==5u) sk[(G)*8+5]=0xFFFFFFFFu; \
    else if (jj==6u) sk[(G)*8+6]=0xFFFFFFFFu; else              sk[(G)*8+7]=0xFFFFFFFFu; } \
  { unsigned bk = sk[(G)*8+0]; unsigned bi = (unsigned)(((G)*8+0)*64 + lane); \
    _Pragma("unroll") \
    for (int j2 = 1; j2 < 8; ++j2) { \
      unsigned k2 = sk[(G)*8+j2]; unsigned i2 = (unsigned)(((G)*8+j2)*64 + lane); \
      bool lt = k2 < bk; bk = lt ? k2 : bk; bi = lt ? i2 : bi; } \
    gk[(G)] = bk; gi[(G)] = bi; } }

__global__ __launch_bounds__(256) void knn_kernel(const float* __restrict__ xyz,
                                                  const float* __restrict__ newxyz,
                                                  int* __restrict__ knn)
{
  __shared__ float4 lp[N_];
  const int b     = blockIdx.x >> 6;
  const int chunk = blockIdx.x & 63;
  const float* xb = xyz + (size_t)b * (N_*3);
  for (int e = threadIdx.x; e < N_; e += 256) {
    float x = xb[e*3+0], y = xb[e*3+1], z = xb[e*3+2];
    float d2 = fadd_(fadd_(fmul_(x,x),fmul_(y,y)),fmul_(z,z));
    lp[e] = make_float4(x,y,z,d2);
  }
  __syncthreads();

  const int wave = threadIdx.x >> 6, lane = threadIdx.x & 63;
  for (int qi = 0; qi < 4; ++qi) {
    const int s  = chunk*16 + wave*4 + qi;
    const int fq = b*S_ + s;
    float qx = newxyz[fq*3+0], qy = newxyz[fq*3+1], qz = newxyz[fq*3+2];
    float s2 = fadd_(fadd_(fmul_(qx,qx),fmul_(qy,qy)),fmul_(qz,qz));

    unsigned sk[64];
#pragma unroll
    for (int j = 0; j < 64; ++j) {
      float4 p = lp[j*64 + lane];
      float dot = fadd_(fadd_(fmul_(qx,p.x),fmul_(qy,p.y)),fmul_(qz,p.z));
      float d   = fadd_(fsub_(s2, fmul_(2.0f,dot)), p.w);
      unsigned u = __float_as_uint(d);
      sk[j] = u ^ ((unsigned)((int)u >> 31) | 0x80000000u);
    }
    unsigned gk[8], gi[8];
#pragma unroll
    for (int g = 0; g < 8; ++g) {
      unsigned bk = sk[g*8+0], bi = (unsigned)((g*8+0)*64 + lane);
#pragma unroll
      for (int j = 1; j < 8; ++j) {
        unsigned k2 = sk[g*8+j]; unsigned i2 = (unsigned)((g*8+j)*64 + lane);
        bool lt = k2 < bk; bk = lt ? k2 : bk; bi = lt ? i2 : bi;
      }
      gk[g]=bk; gi[g]=bi;
    }
    int* ko = knn + (size_t)fq * K_;
    for (int it = 0; it < K_; ++it) {
      unsigned long long c0 = ((unsigned long long)gk[0] << 32) | gi[0];
      unsigned long long c1 = ((unsigned long long)gk[1] << 32) | gi[1];
      unsigned long long c2 = ((unsigned long long)gk[2] << 32) | gi[2];
      unsigned long long c3 = ((unsigned long long)gk[3] << 32) | gi[3];
      unsigned long long c4 = ((unsigned long long)gk[4] << 32) | gi[4];
      unsigned long long c5 = ((unsigned long long)gk[5] << 32) | gi[5];
      unsigned long long c6 = ((unsigned long long)gk[6] << 32) | gi[6];
      unsigned long long c7 = ((unsigned long long)gk[7] << 32) | gi[7];
      c0 = umin64(c0,c1); c2 = umin64(c2,c3); c4 = umin64(c4,c5); c6 = umin64(c6,c7);
      c0 = umin64(c0,c2); c4 = umin64(c4,c6);
      unsigned long long cand = umin64(c0,c4);
#pragma unroll
      for (int m = 1; m <= 32; m <<= 1) {
        unsigned long long o = __shfl_xor(cand, m, 64);
        cand = (o < cand) ? o : cand;
      }
      unsigned widx = (unsigned)cand;
      if (lane == 0) ko[it] = (int)widx;
      unsigned wl = widx & 63u, wj = widx >> 6;
      unsigned g = wj >> 3, jj = wj & 7u;
      bool isw = (lane == (int)wl);
      switch (g) {
        case 0: KNN_REB(0); break;
        case 1: KNN_REB(1); break;
        case 2: KNN_REB(2); break;
        case 3: KNN_REB(3); break;
        case 4: KNN_REB(4); break;
        case 5: KNN_REB(5); break;
        case 6: KNN_REB(6); break;
        default: KNN_REB(7); break;
      }
    }
  }
}

// ---------------------------------------------------------------------------
// Shared MLP helpers. Tile = 4 queries = 128 rows. A stride 104 in LDS.
// ---------------------------------------------------------------------------
template<int KS, int NT>
__device__ __forceinline__ void layer_mfma(const unsigned short* A, const unsigned short* W,
                                           int wstride, f32x4 (&acc)[2][NT], int wave, int lane)
{
  const int quad = lane >> 4, row0 = lane & 15;
  bf16x8 a[2][KS];
#pragma unroll
  for (int m2 = 0; m2 < 2; ++m2)
#pragma unroll
    for (int ks = 0; ks < KS; ++ks)
      a[m2][ks] = *(const bf16x8*)&A[((wave*2+m2)*16 + row0)*104 + ks*32 + quad*8];
#pragma unroll
  for (int m2 = 0; m2 < 2; ++m2)
#pragma unroll
    for (int n = 0; n < NT; ++n)
      acc[m2][n] = (f32x4){0.f,0.f,0.f,0.f};
#pragma unroll
  for (int n = 0; n < NT; ++n) {
#pragma unroll
    for (int ks = 0; ks < KS; ++ks) {
      bf16x8 bfrag = *(const bf16x8*)&W[(n*16 + row0)*wstride + ks*32 + quad*8];
      acc[0][n] = mfma_16x16x32(a[0][ks], bfrag, acc[0][n]);
      acc[1][n] = mfma_16x16x32(a[1][ks], bfrag, acc[1][n]);
    }
  }
}

template<int NT>
__device__ __forceinline__ void stats_ep(const f32x4 (&acc)[2][NT], float* sum, float* sq, int lane)
{
  const int part = blockIdx.x & 63;
  const int col0 = lane & 15;
#pragma unroll
  for (int n = 0; n < NT; ++n) {
    float s = 0.f, q = 0.f;
#pragma unroll
    for (int m2 = 0; m2 < 2; ++m2)
#pragma unroll
      for (int t = 0; t < 4; ++t) { float z = acc[m2][n][t]; s += z; q += z*z; }
    s += __shfl_xor(s, 16, 64); q += __shfl_xor(q, 16, 64);
    s += __shfl_xor(s, 32, 64); q += __shfl_xor(q, 32, 64);
    if (lane < 16) {
      atomicAdd(&sum[part*128 + n*16 + col0], s);
      atomicAdd(&sq [part*128 + n*16 + col0], q);
    }
  }
}

template<int NT>
__device__ __forceinline__ void bn_store(const f32x4 (&acc)[2][NT], unsigned short* A,
                                         const float* lmu, const float* lrsg, const float* lbeta,
                                         int off, int wave, int quad, int col0)
{
#pragma unroll
  for (int n = 0; n < NT; ++n) {
    int c = n*16 + col0;
    float mu = lmu[off+c], rg = lrsg[off+c], bt = lbeta[off+c];
#pragma unroll
    for (int m2 = 0; m2 < 2; ++m2)
#pragma unroll
      for (int t = 0; t < 4; ++t) {
        int row = (wave*2+m2)*16 + quad*4 + t;
        float v = fmaxf((acc[m2][n][t] - mu)*rg + bt, 0.0f);
        A[row*104 + c] = f2bf(v);
      }
  }
}

// pre-BN store into LDS tile with arbitrary stride
template<int NT, int STRIDE>
__device__ __forceinline__ void pre_store(const f32x4 (&acc)[2][NT], unsigned short* A,
                                          int wave, int quad, int col0)
{
#pragma unroll
  for (int n = 0; n < NT; ++n) {
    int c = n*16 + col0;
#pragma unroll
    for (int m2 = 0; m2 < 2; ++m2)
#pragma unroll
      for (int t = 0; t < 4; ++t) {
        int row = (wave*2+m2)*16 + quad*4 + t;
        A[row*STRIDE + c] = f2bf(acc[m2][n][t]);
      }
  }
}

// load one layer's BN params into lmu/lrsg/lbeta[0..cout)
__device__ __forceinline__ void load_bn_layer(const float* stats, const float* g, const float* be,
                                              int L, int cout, float* lmu, float* lrsg, float* lbeta,
                                              int tid)
{
  if (tid < cout) {
    const float* su = stats + (size_t)(2*L)*8192;
    const float* sq = stats + (size_t)(2*L+1)*8192;
    float sm = 0.f, q = 0.f;
    for (int p = 0; p < 64; ++p) { sm += su[p*128+tid]; q += sq[p*128+tid]; }
    float mu  = sm * (1.0f/524288.0f);
    float var = q  * (1.0f/524288.0f) - mu*mu;
    float rs  = rsqrtf(var + 1e-5f);
    lmu[tid]  = mu;
    lrsg[tid] = rs * g[tid];
    lbeta[tid]= be[tid];
  }
}

// gather grouped input tile into sA (stride 104): cols 0..63 pts, 64..66 xyzn, 67..95 zero
__device__ __forceinline__ void gather_tile(const float* xyz, const float* pts,
                                            const float* newxyz, const int* knn,
                                            unsigned short* sA, int tid)
{
  const int r = tid >> 1, half = tid & 1;
  const int ql = r >> 5, kk = r & 31;
  const int fq = blockIdx.x*4 + ql;
  const int b  = fq >> 10;
  const int p  = knn[(size_t)fq*K_ + kk];
  const float4* p4 = (const float4*)(pts + ((size_t)(b<<12) + p) * CPTS);
  ushort8* arow = (ushort8*)&sA[r*104];
  if (half == 0) {
#pragma unroll
    for (int ch = 0; ch < 4; ++ch) {
      float4 a = p4[ch*2], bq = p4[ch*2+1];
      ushort8 v = { f2bf(a.x),f2bf(a.y),f2bf(a.z),f2bf(a.w),
                    f2bf(bq.x),f2bf(bq.y),f2bf(bq.z),f2bf(bq.w) };
      arow[ch] = v;
    }
  } else {
#pragma unroll
    for (int ch = 4; ch < 8; ++ch) {
      float4 a = p4[ch*2], bq = p4[ch*2+1];
      ushort8 v = { f2bf(a.x),f2bf(a.y),f2bf(a.z),f2bf(a.w),
                    f2bf(bq.x),f2bf(bq.y),f2bf(bq.z),f2bf(bq.w) };
      arow[ch] = v;
    }
    const float* xr = xyz + ((size_t)(b<<12) + p)*3;
    float qx = newxyz[fq*3+0], qy = newxyz[fq*3+1], qz = newxyz[fq*3+2];
    ushort8 vx = { f2bf(fsub_(xr[0],qx)), f2bf(fsub_(xr[1],qy)), f2bf(fsub_(xr[2],qz)),
                   0,0,0,0,0 };
    arow[8] = vx;
    ushort8 z = {0,0,0,0,0,0,0,0};
    arow[9] = z; arow[10] = z; arow[11] = z;
  }
}

__device__ __forceinline__ void load_w0(const float* W0, unsigned short* wb, int tid)
{
  const int n = tid >> 2, q = tid & 3;
  const float* wr = W0 + n*67;
#pragma unroll
  for (int ch = 0; ch < 3; ++ch) {
    int c0 = q*24 + ch*8;
    ushort8 v;
#pragma unroll
    for (int j = 0; j < 8; ++j) {
      int cc = c0 + j;
      float f = (cc < 64) ? wr[3+cc] : ((cc < 67) ? wr[cc-64] : 0.0f);
      v[j] = f2bf(f);
    }
    *(ushort8*)&wb[n*104 + c0] = v;
  }
}

__device__ __forceinline__ void load_w1(const float* W1, unsigned short* wb, int tid)
{
  const int n = tid >> 2, k0 = (tid & 3) * 16;
  const float4* w4 = (const float4*)(W1 + n*64 + k0);
#pragma unroll
  for (int i = 0; i < 2; ++i) {
    float4 a = w4[i*2], bq = w4[i*2+1];
    ushort8 v = { f2bf(a.x),f2bf(a.y),f2bf(a.z),f2bf(a.w),
                  f2bf(bq.x),f2bf(bq.y),f2bf(bq.z),f2bf(bq.w) };
    ((ushort8*)&wb[n*72 + k0])[i] = v;
  }
}

__device__ __forceinline__ void load_w2(const float* W2, unsigned short* wb, int tid)
{
  const int n = tid >> 1, k0 = (tid & 1) * 32;
  const float4* w4 = (const float4*)(W2 + n*64 + k0);
#pragma unroll
  for (int i = 0; i < 4; ++i) {
    float4 a = w4[i*2], bq = w4[i*2+1];
    ushort8 v = { f2bf(a.x),f2bf(a.y),f2bf(a.z),f2bf(a.w),
                  f2bf(bq.x),f2bf(bq.y),f2bf(bq.z),f2bf(bq.w) };
    ((ushort8*)&wb[n*72 + k0])[i] = v;
  }
}

// ===========================================================================
// MATERIALIZED PATH (ws_size permitting): each layer computed exactly once.
// z layout: [tile][row(128)][col] bf16, no pad.
// ===========================================================================
__global__ __launch_bounds__(256) void mlpA_kernel(
    const float* __restrict__ xyz, const float* __restrict__ pts,
    const float* __restrict__ W0,
    const float* __restrict__ newxyz, const int* __restrict__ knn,
    float* __restrict__ stats, unsigned short* __restrict__ z0)
{
  __shared__ unsigned short sA[128*104];
  __shared__ unsigned short wb[128*104];   // W0 stride 104, 64 rows
  const int tid  = threadIdx.x;
  const int wave = tid >> 6, lane = tid & 63;
  const int quad = lane >> 4, col0 = lane & 15;

  gather_tile(xyz, pts, newxyz, knn, sA, tid);
  load_w0(W0, wb, tid);
  __syncthreads();

  f32x4 acc0[2][4];
  layer_mfma<3,4>(sA, wb, 104, acc0, wave, lane);
  stats_ep<4>(acc0, stats + 0*8192, stats + 1*8192, lane);
  __syncthreads();                       // all reads of sA done
  pre_store<4,104>(acc0, sA, wave, quad, col0);
  __syncthreads();

  // copy sA (cols 0..63) -> z0, coalesced
  const int r = tid >> 1, hf = tid & 1;
  const ushort8* src = (const ushort8*)&sA[r*104 + hf*32];
  ushort8* dst = (ushort8*)(z0 + (size_t)blockIdx.x*8192 + r*64 + hf*32);
#pragma unroll
  for (int i = 0; i < 4; ++i) dst[i] = src[i];
}

template<int LPREV, int COUT_PREV>
__device__ __forceinline__ void stage_in(const unsigned short* zin,
                                         const float* stats, const float* g, const float* be,
                                         unsigned short* sA, float* lmu, float* lrsg, float* lbeta,
                                         int tid)
{
  const int r = tid >> 1, hf = tid & 1;
  const unsigned short* zp = zin + (size_t)blockIdx.x*8192 + r*64 + hf*32;
  ushort8 in[4];
#pragma unroll
  for (int i = 0; i < 4; ++i) in[i] = ((const ushort8*)zp)[i];
  load_bn_layer(stats, g, be, LPREV, COUT_PREV, lmu, lrsg, lbeta, tid);
  __syncthreads();                       // params visible
#pragma unroll
  for (int i = 0; i < 4; ++i) {
    ushort8 v;
#pragma unroll
    for (int j = 0; j < 8; ++j) {
      int c = hf*32 + i*8 + j;
      float f = bf2f(in[i][j]);
      float x = fmaxf((f - lmu[c])*lrsg[c] + lbeta[c], 0.0f);
      v[j] = f2bf(x);
    }
    ((ushort8*)&sA[r*104 + hf*32])[i] = v;
  }
}

__global__ __launch_bounds__(256) void mlpB_kernel(
    const float* __restrict__ g0, const float* __restrict__ be0,
    const float* __restrict__ W1,
    float* __restrict__ stats,
    const unsigned short* __restrict__ z0, unsigned short* __restrict__ z1)
{
  __shared__ unsigned short sA[128*104];
  __shared__ unsigned short wb[128*72];
  __shared__ float lmu[64], lrsg[64], lbeta[64];
  const int tid  = threadIdx.x;
  const int wave = tid >> 6, lane = tid & 63;
  const int quad = lane >> 4, col0 = lane & 15;

  load_w1(W1, wb, tid);
  stage_in<0,64>(z0, stats, g0, be0, sA, lmu, lrsg, lbeta, tid);
  __syncthreads();

  f32x4 acc1[2][4];
  layer_mfma<2,4>(sA, wb, 72, acc1, wave, lane);
  stats_ep<4>(acc1, stats + 2*8192, stats + 3*8192, lane);
  __syncthreads();
  pre_store<4,104>(acc1, sA, wave, quad, col0);
  __syncthreads();

  const int r = tid >> 1, hf = tid & 1;
  const ushort8* src = (const ushort8*)&sA[r*104 + hf*32];
  ushort8* dst = (ushort8*)(z1 + (size_t)blockIdx.x*8192 + r*64 + hf*32);
#pragma unroll
  for (int i = 0; i < 4; ++i) dst[i] = src[i];
}

__global__ __launch_bounds__(256) void mlpC_kernel(
    const float* __restrict__ g1, const float* __restrict__ be1,
    const float* __restrict__ W2,
    float* __restrict__ stats,
    const unsigned short* __restrict__ z1, unsigned short* __restrict__ z2)
{
  __shared__ unsigned short BUF[22528];   // A: [0,13312) stride 104; W: [13312,22528) stride 72
  __shared__ float lmu[64], lrsg[64], lbeta[64];
  unsigned short* sA = BUF;
  unsigned short* wb = BUF + 13312;
  const int tid  = threadIdx.x;
  const int wave = tid >> 6, lane = tid & 63;
  const int quad = lane >> 4, col0 = lane & 15;

  load_w2(W2, wb, tid);
  stage_in<1,64>(z1, stats, g1, be1, sA, lmu, lrsg, lbeta, tid);
  __syncthreads();

  f32x4 acc2[2][8];
  layer_mfma<2,8>(sA, wb, 72, acc2, wave, lane);
  stats_ep<8>(acc2, stats + 4*8192, stats + 5*8192, lane);
  __syncthreads();                       // BUF fully dead, reuse as zout stride 136
  pre_store<8,136>(acc2, BUF, wave, quad, col0);
  __syncthreads();

  const int r = tid >> 1, hf = tid & 1;
  const ushort8* src = (const ushort8*)&BUF[r*136 + hf*64];
  ushort8* dst = (ushort8*)(z2 + (size_t)blockIdx.x*16384 + r*128 + hf*64);
#pragma unroll
  for (int i = 0; i < 8; ++i) dst[i] = src[i];
}

typedef unsigned short ushort4v __attribute__((ext_vector_type(4)));

__global__ __launch_bounds__(256) void mlpD_kernel(
    const float* __restrict__ g2, const float* __restrict__ be2,
    const float* __restrict__ stats,
    const unsigned short* __restrict__ z2, float* __restrict__ out1)
{
  __shared__ float lmu[128], lrsg[128], lbeta[128];
  const int tid = threadIdx.x;
  load_bn_layer(stats, g2, be2, 2, 128, lmu, lrsg, lbeta, tid);
  __syncthreads();

  const int wq = tid >> 5, l32 = tid & 31;
  const int fq = blockIdx.x*8 + wq;
  const int tile = fq >> 2, ql = fq & 3;
  const int c0 = l32 * 4;
  const unsigned short* zp = z2 + ((size_t)tile*128 + ql*32)*128 + c0;

  float mu[4], rg[4], bt[4], mx[4];
#pragma unroll
  for (int j = 0; j < 4; ++j) {
    mu[j] = lmu[c0+j]; rg[j] = lrsg[c0+j]; bt[j] = lbeta[c0+j];
    mx[j] = -INFINITY;
  }
  for (int r = 0; r < 32; ++r) {
    ushort4v v = *(const ushort4v*)(zp + (size_t)r*128);
#pragma unroll
    for (int j = 0; j < 4; ++j) {
      float f = bf2f(v[j]);
      float x = fmaxf((f - mu[j])*rg[j] + bt[j], 0.0f);
      mx[j] = fmaxf(mx[j], x);
    }
  }
  float4 o = make_float4(mx[0], mx[1], mx[2], mx[3]);
  *(float4*)(out1 + (size_t)fq*128 + c0) = o;
}

// ===========================================================================
// FALLBACK PATH: 4-stage recompute chain (round-5 proven).
// ===========================================================================
template<int STAGE>
__global__ __launch_bounds__(256) void mlp_kernel(
    const float* __restrict__ xyz, const float* __restrict__ pts,
    const float* __restrict__ W0, const float* __restrict__ g0, const float* __restrict__ be0,
    const float* __restrict__ W1, const float* __restrict__ g1, const float* __restrict__ be1,
    const float* __restrict__ W2, const float* __restrict__ g2, const float* __restrict__ be2,
    const float* __restrict__ newxyz, const int* __restrict__ knn,
    float* __restrict__ stats, float* __restrict__ out1)
{
  __shared__ unsigned short sA[128*104];
  __shared__ unsigned short wb[128*104];
  __shared__ float lmu[256], lrsg[256], lbeta[256];

  const int tid  = threadIdx.x;
  const int wave = tid >> 6, lane = tid & 63;
  const int quad = lane >> 4, col0 = lane & 15;

  {
    const int nl = STAGE - 1;
    const int   couts[3] = {64,64,128};
    const int   offs[3]  = {0,64,128};
    const float* gs[3]   = {g0,g1,g2};
    const float* bs[3]   = {be0,be1,be2};
    for (int l = 0; l < nl; ++l) {
      if (tid < couts[l]) {
        const float* su = stats + (size_t)(2*l)*8192;
        const float* sq = stats + (size_t)(2*l+1)*8192;
        float sm = 0.f, q = 0.f;
        for (int p = 0; p < 64; ++p) { sm += su[p*128+tid]; q += sq[p*128+tid]; }
        float mu  = sm * (1.0f/524288.0f);
        float var = q  * (1.0f/524288.0f) - mu*mu;
        float rs  = rsqrtf(var + 1e-5f);
        lmu [offs[l]+tid] = mu;
        lrsg[offs[l]+tid] = rs * gs[l][tid];
        lbeta[offs[l]+tid] = bs[l][tid];
      }
    }
  }

  gather_tile(xyz, pts, newxyz, knn, sA, tid);
  load_w0(W0, wb, tid);
  __syncthreads();

  f32x4 acc0[2][4];
  layer_mfma<3,4>(sA, wb, 104, acc0, wave, lane);
  __syncthreads();
  if constexpr (STAGE == 1) { stats_ep<4>(acc0, stats + 0*8192, stats + 1*8192, lane); return; }

  bn_store<4>(acc0, sA, lmu, lrsg, lbeta, 0, wave, quad, col0);
  load_w1(W1, wb, tid);
  __syncthreads();

  f32x4 acc1[2][4];
  layer_mfma<2,4>(sA, wb, 72, acc1, wave, lane);
  __syncthreads();
  if constexpr (STAGE == 2) { stats_ep<4>(acc1, stats + 2*8192, stats + 3*8192, lane); return; }

  bn_store<4>(acc1, sA, lmu, lrsg, lbeta, 64, wave, quad, col0);
  load_w2(W2, wb, tid);
  __syncthreads();

  f32x4 acc2[2][8];
  layer_mfma<2,8>(sA, wb, 72, acc2, wave, lane);
  if constexpr (STAGE == 3) { stats_ep<8>(acc2, stats + 4*8192, stats + 5*8192, lane); return; }

  {
    const int fq = blockIdx.x*4 + wave;
#pragma unroll
    for (int n = 0; n < 8; ++n) {
      int c = n*16 + col0;
      float mu = lmu[128+c], rg = lrsg[128+c], bt = lbeta[128+c];
      float mx = -INFINITY;
#pragma unroll
      for (int m2 = 0; m2 < 2; ++m2)
#pragma unroll
        for (int t = 0; t < 4; ++t) {
          float v = fmaxf((acc2[m2][n][t] - mu)*rg + bt, 0.0f);
          mx = fmaxf(mx, v);
        }
      mx = fmaxf(mx, __shfl_xor(mx, 16, 64));
      mx = fmaxf(mx, __shfl_xor(mx, 32, 64));
      if (lane < 16) out1[(size_t)fq*128 + c] = mx;
    }
  }
}

// ---------------------------------------------------------------------------
extern "C" void kernel_launch(void* const* d_in, const int* in_sizes, int n_in,
                              void* d_out, int out_size, void* d_ws, size_t ws_size,
                              hipStream_t stream)
{
  (void)in_sizes; (void)n_in; (void)out_size;
  const float* xyz  = (const float*)d_in[0];
  const float* pts  = (const float*)d_in[1];
  const float* W0   = (const float*)d_in[2];
  const float* g0   = (const float*)d_in[3];
  const float* be0  = (const float*)d_in[4];
  const float* W1   = (const float*)d_in[5];
  const float* g1   = (const float*)d_in[6];
  const float* be1  = (const float*)d_in[7];
  const float* W2   = (const float*)d_in[8];
  const float* g2   = (const float*)d_in[9];
  const float* be2  = (const float*)d_in[10];

  float* out  = (float*)d_out;                   // new_xyz: 16*1024*3
  float* out1 = out + (size_t)B_*S_*3;           // features: 16*1024*128

  // ws layout
  const size_t knn_off   = 0;
  const size_t stats_off = 2097152;              // 2 MB
  const size_t z0_off    = 2293760;
  const size_t z1_off    = z0_off + 67108864;    // +64 MB
  const size_t z2_off    = z1_off + 67108864;    // +64 MB
  const size_t need      = z2_off + 134217728;   // +128 MB = 270,729,216

  int*   knn   = (int*)((char*)d_ws + knn_off);
  float* stats = (float*)((char*)d_ws + stats_off);

  hipMemsetAsync(stats, 0, (size_t)6*8192*sizeof(float), stream);
  fps_kernel<<<16, 256, 0, stream>>>(xyz, out);
  knn_kernel<<<1024, 256, 0, stream>>>(xyz, out, knn);

  if (ws_size >= need) {
    unsigned short* z0 = (unsigned short*)((char*)d_ws + z0_off);
    unsigned short* z1 = (unsigned short*)((char*)d_ws + z1_off);
    unsigned short* z2 = (unsigned short*)((char*)d_ws + z2_off);
    mlpA_kernel<<<4096, 256, 0, stream>>>(xyz, pts, W0, out, knn, stats, z0);
    mlpB_kernel<<<4096, 256, 0, stream>>>(g0, be0, W1, stats, z0, z1);
    mlpC_kernel<<<4096, 256, 0, stream>>>(g1, be1, W2, stats, z1, z2);
    mlpD_kernel<<<2048, 256, 0, stream>>>(g2, be2, stats, z2, out1);
  } else {
    mlp_kernel<1><<<4096, 256, 0, stream>>>(xyz, pts, W0,g0,be0, W1,g1,be1, W2,g2,be2, out, knn, stats, out1);
    mlp_kernel<2><<<4096, 256, 0, stream>>>(xyz, pts, W0,g0,be0, W1,g1,be1, W2,g2,be2, out, knn, stats, out1);
    mlp_kernel<3><<<4096, 256, 0, stream>>>(xyz, pts, W0,g0,be0, W1,g1,be1, W2,g2,be2, out, knn, stats, out1);
    mlp_kernel<4><<<4096, 256, 0, stream>>>(xyz, pts, W0,g0,be0, W1,g1,be1, W2,g2,be2, out, knn, stats, out1);
  }
}

// Round 8
// 1345.608 us; speedup vs baseline: 1.4390x; 1.0335x over previous
//
#include <hip/hip_runtime.h>
#include <stdint.h>

#define B_    16
#define N_    4096
#define CPTS  64
#define S_    1024
#define K_    32

typedef __bf16 bf16x8 __attribute__((ext_vector_type(8)));
typedef float  f32x4  __attribute__((ext_vector_type(4)));
typedef unsigned short ushort8 __attribute__((ext_vector_type(8)));

__device__ __forceinline__ float fmul_(float a, float b){ return __fmul_rn(a,b); }
__device__ __forceinline__ float fadd_(float a, float b){ return __fadd_rn(a,b); }
__device__ __forceinline__ float fsub_(float a, float b){ return __fsub_rn(a,b); }

__device__ __forceinline__ unsigned short f2bf(float f){
  unsigned u = __float_as_uint(f);
  unsigned r = (u + 0x7FFFu + ((u >> 16) & 1u)) >> 16;
  return (unsigned short)r;
}

__device__ __forceinline__ f32x4 mfma_16x16x32(bf16x8 a, bf16x8 b, f32x4 c){
  return __builtin_amdgcn_mfma_f32_16x16x32_bf16(a, b, c, 0, 0, 0);
}

__device__ __forceinline__ unsigned long long umin64(unsigned long long a, unsigned long long b){
  return b < a ? b : a;
}
__device__ __forceinline__ unsigned long long umax64(unsigned long long a, unsigned long long b){
  return a < b ? b : a;
}

// DPP lane move: invalid source lanes keep old value (= identity for min/max).
template<int CTRL>
__device__ __forceinline__ unsigned dppmove(unsigned v){
  return (unsigned)__builtin_amdgcn_update_dpp((int)v, (int)v, CTRL, 0xF, 0xF, false);
}
__device__ __forceinline__ unsigned wave_umax_dpp(unsigned v){
  unsigned t;
  t = dppmove<0x111>(v); v = v > t ? v : t;
  t = dppmove<0x112>(v); v = v > t ? v : t;
  t = dppmove<0x114>(v); v = v > t ? v : t;
  t = dppmove<0x118>(v); v = v > t ? v : t;
  t = dppmove<0x142>(v); v = v > t ? v : t;
  t = dppmove<0x143>(v); v = v > t ? v : t;
  return (unsigned)__builtin_amdgcn_readlane((int)v, 63);
}
__device__ __forceinline__ unsigned wave_umin_dpp(unsigned v){
  unsigned t;
  t = dppmove<0x111>(v); v = v < t ? v : t;
  t = dppmove<0x112>(v); v = v < t ? v : t;
  t = dppmove<0x114>(v); v = v < t ? v : t;
  t = dppmove<0x118>(v); v = v < t ? v : t;
  t = dppmove<0x142>(v); v = v < t ? v : t;
  t = dppmove<0x143>(v); v = v < t ? v : t;
  return (unsigned)__builtin_amdgcn_readlane((int)v, 63);
}

// ---------------------------------------------------------------------------
// FPS (round-5 proven): one block per batch, 256 threads, 16 pts/thread.
// Also zeroes the stats buffer (replaces the hipMemsetAsync dispatch).
// ---------------------------------------------------------------------------
__global__ __launch_bounds__(256) void fps_kernel(const float* __restrict__ xyz,
                                                  float* __restrict__ out_newxyz,
                                                  float* __restrict__ stats)
{
  const int b   = blockIdx.x;
  const int tid = threadIdx.x;
  const int wave = tid >> 6;
  __shared__ float4 lp[N_];
  __shared__ unsigned long long wc[2][4];
  __shared__ int fhist[S_ + 1];

  // zero stats: 6*8192 floats = 12288 float4, 16 blocks x 256 thr x 3 each
  {
    float4* s4 = (float4*)stats;
    const int base = (b*256 + tid)*3;
    const float4 z = make_float4(0.f,0.f,0.f,0.f);
    s4[base+0] = z; s4[base+1] = z; s4[base+2] = z;
  }

  const float* xb = xyz + (size_t)b * (N_*3);
  float px[16], py[16], pz[16], dmin[16];
#pragma unroll
  for (int i = 0; i < 16; ++i) {
    int n = i*256 + tid;
    float x = xb[n*3+0], y = xb[n*3+1], z = xb[n*3+2];
    lp[n] = make_float4(x,y,z,0.0f);
    px[i]=x; py[i]=y; pz[i]=z;
    dmin[i] = INFINITY;
  }
  if (tid == 0) fhist[0] = 0;
  __syncthreads();

  int far = 0;
  for (int step = 0; step < S_; ++step) {
    float4 cp = lp[far];
    float cx = cp.x, cy = cp.y, cz = cp.z;
    float bv = -1.0f; unsigned bidx = 0;
#pragma unroll
    for (int i = 0; i < 16; ++i) {
      float dx = fsub_(px[i],cx), dy = fsub_(py[i],cy), dz = fsub_(pz[i],cz);
      float d  = fadd_(fadd_(fmul_(dx,dx),fmul_(dy,dy)),fmul_(dz,dz));
      float dm = fminf(dmin[i], d);
      dmin[i] = dm;
      bool gt = dm > bv;
      bv   = gt ? dm : bv;
      bidx = gt ? (unsigned)(i*256 + tid) : bidx;
    }
    unsigned bvb  = __float_as_uint(bv);
    unsigned wmax = wave_umax_dpp(bvb);
    unsigned cand = (bvb == wmax) ? ~bidx : 0u;
    unsigned winv = wave_umax_dpp(cand);
    unsigned long long kv = ((unsigned long long)wmax << 32) | winv;

    int par = step & 1;
    if ((tid & 63) == 0) wc[par][wave] = kv;
    __syncthreads();
    unsigned long long b0 = umax64(wc[par][0], wc[par][1]);
    unsigned long long b1 = umax64(wc[par][2], wc[par][3]);
    far = (int)(~(unsigned)umax64(b0, b1));
    if (tid == 0) fhist[step + 1] = far;
  }
  __syncthreads();

  float* ob = out_newxyz + (size_t)b*S_*3;
#pragma unroll
  for (int j = 0; j < 4; ++j) {
    int s = j*256 + tid;
    float4 p = lp[fhist[s]];
    ob[s*3+0] = p.x; ob[s*3+1] = p.y; ob[s*3+2] = p.z;
  }
}

// ---------------------------------------------------------------------------
// kNN: top-32 of 4096 per query, wave-per-query. Extraction loop is now
// all-VALU: per-lane u64 tree + two-phase DPP wave-min (no ds_bpermute).
// ---------------------------------------------------------------------------
#define KNN_REB(G) { \
  if (isw) { \
    if      (jj==0u) sk[(G)*8+0]=0xFFFFFFFFu; else if (jj==1u) sk[(G)*8+1]=0xFFFFFFFFu; \
    else if (jj==2u) sk[(G)*8+2]=0xFFFFFFFFu; else if (jj==3u) sk[(G)*8+3]=0xFFFFFFFFu; \
    else if (jj==4u) sk[(G)*8+4]=0xFFFFFFFFu; else if (jj==5u) sk[(G)*8+5]=0xFFFFFFFFu; \
    else if (jj==6u) sk[(G)*8+6]=0xFFFFFFFFu; else              sk[(G)*8+7]=0xFFFFFFFFu; } \
  { unsigned bk = sk[(G)*8+0]; unsigned bi = (unsigned)(((G)*8+0)*64 + lane); \
    _Pragma("unroll") \
    for (int j2 = 1; j2 < 8; ++j2) { \
      unsigned k2 = sk[(G)*8+j2]; unsigned i2 = (unsigned)(((G)*8+j2)*64 + lane); \
      bool lt = k2 < bk; bk = lt ? k2 : bk; bi = lt ? i2 : bi; } \
    gk[(G)] = bk; gi[(G)] = bi; } }

__global__ __launch_bounds__(256) void knn_kernel(const float* __restrict__ xyz,
                                                  const float* __restrict__ newxyz,
                                                  int* __restrict__ knn)
{
  __shared__ float4 lp[N_];
  const int b     = blockIdx.x >> 6;
  const int chunk = blockIdx.x & 63;
  const float* xb = xyz + (size_t)b * (N_*3);
  for (int e = threadIdx.x; e < N_; e += 256) {
    float x = xb[e*3+0], y = xb[e*3+1], z = xb[e*3+2];
    float d2 = fadd_(fadd_(fmul_(x,x),fmul_(y,y)),fmul_(z,z));
    lp[e] = make_float4(x,y,z,d2);
  }
  __syncthreads();

  const int wave = threadIdx.x >> 6, lane = threadIdx.x & 63;
  for (int qi = 0; qi < 4; ++qi) {
    const int s  = chunk*16 + wave*4 + qi;
    const int fq = b*S_ + s;
    float qx = newxyz[fq*3+0], qy = newxyz[fq*3+1], qz = newxyz[fq*3+2];
    float s2 = fadd_(fadd_(fmul_(qx,qx),fmul_(qy,qy)),fmul_(qz,qz));

    unsigned sk[64];
#pragma unroll
    for (int j = 0; j < 64; ++j) {
      float4 p = lp[j*64 + lane];
      float dot = fadd_(fadd_(fmul_(qx,p.x),fmul_(qy,p.y)),fmul_(qz,p.z));
      float d   = fadd_(fsub_(s2, fmul_(2.0f,dot)), p.w);
      unsigned u = __float_as_uint(d);
      sk[j] = u ^ ((unsigned)((int)u >> 31) | 0x80000000u);  // sortable
    }
    unsigned gk[8], gi[8];
#pragma unroll
    for (int g = 0; g < 8; ++g) {
      unsigned bk = sk[g*8+0], bi = (unsigned)((g*8+0)*64 + lane);
#pragma unroll
      for (int j = 1; j < 8; ++j) {
        unsigned k2 = sk[g*8+j]; unsigned i2 = (unsigned)((g*8+j)*64 + lane);
        bool lt = k2 < bk; bk = lt ? k2 : bk; bi = lt ? i2 : bi;
      }
      gk[g]=bk; gi[g]=bi;
    }
    int* ko = knn + (size_t)fq * K_;
    for (int it = 0; it < K_; ++it) {
      unsigned long long c0 = ((unsigned long long)gk[0] << 32) | gi[0];
      unsigned long long c1 = ((unsigned long long)gk[1] << 32) | gi[1];
      unsigned long long c2 = ((unsigned long long)gk[2] << 32) | gi[2];
      unsigned long long c3 = ((unsigned long long)gk[3] << 32) | gi[3];
      unsigned long long c4 = ((unsigned long long)gk[4] << 32) | gi[4];
      unsigned long long c5 = ((unsigned long long)gk[5] << 32) | gi[5];
      unsigned long long c6 = ((unsigned long long)gk[6] << 32) | gi[6];
      unsigned long long c7 = ((unsigned long long)gk[7] << 32) | gi[7];
      c0 = umin64(c0,c1); c2 = umin64(c2,c3); c4 = umin64(c4,c5); c6 = umin64(c6,c7);
      c0 = umin64(c0,c2); c4 = umin64(c4,c6);
      unsigned long long cand = umin64(c0,c4);
      unsigned lkey = (unsigned)(cand >> 32);
      unsigned lidx = (unsigned)cand;
      // two-phase DPP wave-min (all VALU, no DS):
      unsigned wkey = wave_umin_dpp(lkey);
      unsigned widx = wave_umin_dpp((lkey == wkey) ? lidx : 0xFFFFFFFFu);
      if (lane == 0) ko[it] = (int)widx;
      unsigned wl = widx & 63u, wj = widx >> 6;   // wj, g, jj are wave-uniform
      unsigned g = wj >> 3, jj = wj & 7u;
      bool isw = (lane == (int)wl);
      switch (g) {
        case 0: KNN_REB(0); break;
        case 1: KNN_REB(1); break;
        case 2: KNN_REB(2); break;
        case 3: KNN_REB(3); break;
        case 4: KNN_REB(4); break;
        case 5: KNN_REB(5); break;
        case 6: KNN_REB(6); break;
        default: KNN_REB(7); break;
      }
    }
  }
}

// ---------------------------------------------------------------------------
// MLP chain (round-5 proven 4-stage recompute). Tile = 4 queries = 128 rows.
// A layout (K): cols 0..63 = points, 64..66 = xyz-norm, 67..95 = zero.
// ---------------------------------------------------------------------------
template<int KS, int NT>
__device__ __forceinline__ void layer_mfma(const unsigned short* A, const unsigned short* W,
                                           int wstride, f32x4 (&acc)[2][NT], int wave, int lane)
{
  const int quad = lane >> 4, row0 = lane & 15;
  bf16x8 a[2][KS];
#pragma unroll
  for (int m2 = 0; m2 < 2; ++m2)
#pragma unroll
    for (int ks = 0; ks < KS; ++ks)
      a[m2][ks] = *(const bf16x8*)&A[((wave*2+m2)*16 + row0)*104 + ks*32 + quad*8];
#pragma unroll
  for (int m2 = 0; m2 < 2; ++m2)
#pragma unroll
    for (int n = 0; n < NT; ++n)
      acc[m2][n] = (f32x4){0.f,0.f,0.f,0.f};
#pragma unroll
  for (int n = 0; n < NT; ++n) {
#pragma unroll
    for (int ks = 0; ks < KS; ++ks) {
      bf16x8 bfrag = *(const bf16x8*)&W[(n*16 + row0)*wstride + ks*32 + quad*8];
      acc[0][n] = mfma_16x16x32(a[0][ks], bfrag, acc[0][n]);
      acc[1][n] = mfma_16x16x32(a[1][ks], bfrag, acc[1][n]);
    }
  }
}

template<int NT>
__device__ __forceinline__ void stats_ep(const f32x4 (&acc)[2][NT], float* sum, float* sq, int lane)
{
  const int part = blockIdx.x & 63;
  const int col0 = lane & 15;
#pragma unroll
  for (int n = 0; n < NT; ++n) {
    float s = 0.f, q = 0.f;
#pragma unroll
    for (int m2 = 0; m2 < 2; ++m2)
#pragma unroll
      for (int t = 0; t < 4; ++t) { float z = acc[m2][n][t]; s += z; q += z*z; }
    s += __shfl_xor(s, 16, 64); q += __shfl_xor(q, 16, 64);
    s += __shfl_xor(s, 32, 64); q += __shfl_xor(q, 32, 64);
    if (lane < 16) {
      atomicAdd(&sum[part*128 + n*16 + col0], s);
      atomicAdd(&sq [part*128 + n*16 + col0], q);
    }
  }
}

template<int NT>
__device__ __forceinline__ void bn_store(const f32x4 (&acc)[2][NT], unsigned short* A,
                                         const float* lmu, const float* lrsg, const float* lbeta,
                                         int off, int wave, int quad, int col0)
{
#pragma unroll
  for (int n = 0; n < NT; ++n) {
    int c = n*16 + col0;
    float mu = lmu[off+c], rg = lrsg[off+c], bt = lbeta[off+c];
#pragma unroll
    for (int m2 = 0; m2 < 2; ++m2)
#pragma unroll
      for (int t = 0; t < 4; ++t) {
        int row = (wave*2+m2)*16 + quad*4 + t;
        float v = fmaxf((acc[m2][n][t] - mu)*rg + bt, 0.0f);
        A[row*104 + c] = f2bf(v);
      }
  }
}

__device__ __forceinline__ void gather_tile(const float* xyz, const float* pts,
                                            const float* newxyz, const int* knn,
                                            unsigned short* sA, int tid)
{
  const int r = tid >> 1, half = tid & 1;
  const int ql = r >> 5, kk = r & 31;
  const int fq = blockIdx.x*4 + ql;
  const int b  = fq >> 10;
  const int p  = knn[(size_t)fq*K_ + kk];
  const float4* p4 = (const float4*)(pts + ((size_t)(b<<12) + p) * CPTS);
  ushort8* arow = (ushort8*)&sA[r*104];
  if (half == 0) {
#pragma unroll
    for (int ch = 0; ch < 4; ++ch) {
      float4 a = p4[ch*2], bq = p4[ch*2+1];
      ushort8 v = { f2bf(a.x),f2bf(a.y),f2bf(a.z),f2bf(a.w),
                    f2bf(bq.x),f2bf(bq.y),f2bf(bq.z),f2bf(bq.w) };
      arow[ch] = v;
    }
  } else {
#pragma unroll
    for (int ch = 4; ch < 8; ++ch) {
      float4 a = p4[ch*2], bq = p4[ch*2+1];
      ushort8 v = { f2bf(a.x),f2bf(a.y),f2bf(a.z),f2bf(a.w),
                    f2bf(bq.x),f2bf(bq.y),f2bf(bq.z),f2bf(bq.w) };
      arow[ch] = v;
    }
    const float* xr = xyz + ((size_t)(b<<12) + p)*3;
    float qx = newxyz[fq*3+0], qy = newxyz[fq*3+1], qz = newxyz[fq*3+2];
    ushort8 vx = { f2bf(fsub_(xr[0],qx)), f2bf(fsub_(xr[1],qy)), f2bf(fsub_(xr[2],qz)),
                   0,0,0,0,0 };
    arow[8] = vx;
    ushort8 z = {0,0,0,0,0,0,0,0};
    arow[9] = z; arow[10] = z; arow[11] = z;
  }
}

__device__ __forceinline__ void load_w0(const float* W0, unsigned short* wb, int tid)
{
  const int n = tid >> 2, q = tid & 3;
  const float* wr = W0 + n*67;
#pragma unroll
  for (int ch = 0; ch < 3; ++ch) {
    int c0 = q*24 + ch*8;
    ushort8 v;
#pragma unroll
    for (int j = 0; j < 8; ++j) {
      int cc = c0 + j;
      float f = (cc < 64) ? wr[3+cc] : ((cc < 67) ? wr[cc-64] : 0.0f);
      v[j] = f2bf(f);
    }
    *(ushort8*)&wb[n*104 + c0] = v;
  }
}

__device__ __forceinline__ void load_w1(const float* W1, unsigned short* wb, int tid)
{
  const int n = tid >> 2, k0 = (tid & 3) * 16;
  const float4* w4 = (const float4*)(W1 + n*64 + k0);
#pragma unroll
  for (int i = 0; i < 2; ++i) {
    float4 a = w4[i*2], bq = w4[i*2+1];
    ushort8 v = { f2bf(a.x),f2bf(a.y),f2bf(a.z),f2bf(a.w),
                  f2bf(bq.x),f2bf(bq.y),f2bf(bq.z),f2bf(bq.w) };
    ((ushort8*)&wb[n*72 + k0])[i] = v;
  }
}

__device__ __forceinline__ void load_w2(const float* W2, unsigned short* wb, int tid)
{
  const int n = tid >> 1, k0 = (tid & 1) * 32;
  const float4* w4 = (const float4*)(W2 + n*64 + k0);
#pragma unroll
  for (int i = 0; i < 4; ++i) {
    float4 a = w4[i*2], bq = w4[i*2+1];
    ushort8 v = { f2bf(a.x),f2bf(a.y),f2bf(a.z),f2bf(a.w),
                  f2bf(bq.x),f2bf(bq.y),f2bf(bq.z),f2bf(bq.w) };
    ((ushort8*)&wb[n*72 + k0])[i] = v;
  }
}

template<int STAGE>
__global__ __launch_bounds__(256) void mlp_kernel(
    const float* __restrict__ xyz, const float* __restrict__ pts,
    const float* __restrict__ W0, const float* __restrict__ g0, const float* __restrict__ be0,
    const float* __restrict__ W1, const float* __restrict__ g1, const float* __restrict__ be1,
    const float* __restrict__ W2, const float* __restrict__ g2, const float* __restrict__ be2,
    const float* __restrict__ newxyz, const int* __restrict__ knn,
    float* __restrict__ stats, float* __restrict__ out1)
{
  __shared__ unsigned short sA[128*104];
  __shared__ unsigned short wb[128*104];
  __shared__ float lmu[256], lrsg[256], lbeta[256];

  const int tid  = threadIdx.x;
  const int wave = tid >> 6, lane = tid & 63;
  const int quad = lane >> 4, col0 = lane & 15;

  {
    const int nl = STAGE - 1;
    const int   couts[3] = {64,64,128};
    const int   offs[3]  = {0,64,128};
    const float* gs[3]   = {g0,g1,g2};
    const float* bs[3]   = {be0,be1,be2};
    for (int l = 0; l < nl; ++l) {
      if (tid < couts[l]) {
        const float* su = stats + (size_t)(2*l)*8192;
        const float* sq = stats + (size_t)(2*l+1)*8192;
        float sm = 0.f, q = 0.f;
        for (int p = 0; p < 64; ++p) { sm += su[p*128+tid]; q += sq[p*128+tid]; }
        float mu  = sm * (1.0f/524288.0f);
        float var = q  * (1.0f/524288.0f) - mu*mu;
        float rs  = rsqrtf(var + 1e-5f);
        lmu [offs[l]+tid] = mu;
        lrsg[offs[l]+tid] = rs * gs[l][tid];
        lbeta[offs[l]+tid] = bs[l][tid];
      }
    }
  }

  gather_tile(xyz, pts, newxyz, knn, sA, tid);
  load_w0(W0, wb, tid);
  __syncthreads();

  f32x4 acc0[2][4];
  layer_mfma<3,4>(sA, wb, 104, acc0, wave, lane);
  __syncthreads();
  if constexpr (STAGE == 1) { stats_ep<4>(acc0, stats + 0*8192, stats + 1*8192, lane); return; }

  bn_store<4>(acc0, sA, lmu, lrsg, lbeta, 0, wave, quad, col0);
  load_w1(W1, wb, tid);
  __syncthreads();

  f32x4 acc1[2][4];
  layer_mfma<2,4>(sA, wb, 72, acc1, wave, lane);
  __syncthreads();
  if constexpr (STAGE == 2) { stats_ep<4>(acc1, stats + 2*8192, stats + 3*8192, lane); return; }

  bn_store<4>(acc1, sA, lmu, lrsg, lbeta, 64, wave, quad, col0);
  load_w2(W2, wb, tid);
  __syncthreads();

  f32x4 acc2[2][8];
  layer_mfma<2,8>(sA, wb, 72, acc2, wave, lane);
  if constexpr (STAGE == 3) { stats_ep<8>(acc2, stats + 4*8192, stats + 5*8192, lane); return; }

  {
    const int fq = blockIdx.x*4 + wave;
#pragma unroll
    for (int n = 0; n < 8; ++n) {
      int c = n*16 + col0;
      float mu = lmu[128+c], rg = lrsg[128+c], bt = lbeta[128+c];
      float mx = -INFINITY;
#pragma unroll
      for (int m2 = 0; m2 < 2; ++m2)
#pragma unroll
        for (int t = 0; t < 4; ++t) {
          float v = fmaxf((acc2[m2][n][t] - mu)*rg + bt, 0.0f);
          mx = fmaxf(mx, v);
        }
      mx = fmaxf(mx, __shfl_xor(mx, 16, 64));
      mx = fmaxf(mx, __shfl_xor(mx, 32, 64));
      if (lane < 16) out1[(size_t)fq*128 + c] = mx;
    }
  }
}

// ---------------------------------------------------------------------------
extern "C" void kernel_launch(void* const* d_in, const int* in_sizes, int n_in,
                              void* d_out, int out_size, void* d_ws, size_t ws_size,
                              hipStream_t stream)
{
  (void)in_sizes; (void)n_in; (void)out_size; (void)ws_size;
  const float* xyz  = (const float*)d_in[0];
  const float* pts  = (const float*)d_in[1];
  const float* W0   = (const float*)d_in[2];
  const float* g0   = (const float*)d_in[3];
  const float* be0  = (const float*)d_in[4];
  const float* W1   = (const float*)d_in[5];
  const float* g1   = (const float*)d_in[6];
  const float* be1  = (const float*)d_in[7];
  const float* W2   = (const float*)d_in[8];
  const float* g2   = (const float*)d_in[9];
  const float* be2  = (const float*)d_in[10];

  float* out  = (float*)d_out;                   // new_xyz: 16*1024*3
  float* out1 = out + (size_t)B_*S_*3;           // features: 16*1024*128
  int*   knn   = (int*)d_ws;                                     // 2 MB
  float* stats = (float*)((char*)d_ws + (size_t)B_*S_*K_*4);     // 6*8192 floats

  fps_kernel<<<16, 256, 0, stream>>>(xyz, out, stats);
  knn_kernel<<<1024, 256, 0, stream>>>(xyz, out, knn);
  mlp_kernel<1><<<4096, 256, 0, stream>>>(xyz, pts, W0,g0,be0, W1,g1,be1, W2,g2,be2, out, knn, stats, out1);
  mlp_kernel<2><<<4096, 256, 0, stream>>>(xyz, pts, W0,g0,be0, W1,g1,be1, W2,g2,be2, out, knn, stats, out1);
  mlp_kernel<3><<<4096, 256, 0, stream>>>(xyz, pts, W0,g0,be0, W1,g1,be1, W2,g2,be2, out, knn, stats, out1);
  mlp_kernel<4><<<4096, 256, 0, stream>>>(xyz, pts, W0,g0,be0, W1,g1,be1, W2,g2,be2, out, knn, stats, out1);
}